// Round 6
// baseline (141.478 us; speedup 1.0000x reference)
//
#include <hip/hip_runtime.h>
#include <math.h>

#define N_FILT 64
#define IMG_DIM 256
#define IMG_SZ (256*256)
#define HDIM 1024
#define NBATCH 512

// ws layout (131,328 B total):
//   int meta[64]: [0..15]=aloY [16..31]=ahiY   (16 n-groups of 4, stage 1)
//                 [32..47]=lo4X (granule-aligned) [48..63]=hiX (16 m-groups of 4)
//   byte 256           : fyg [16][256][4] float (gamma/SY folded, zero-filled) 64 KiB
//   byte 256+65536     : fxg [16][256][4] float (1/SX folded, zero-filled)     64 KiB

// async DMA: one wave-issue copies 64 lanes x 16B = 1KB row into LDS at
// wave-uniform base + lane*16 (gfx950 global_load_lds_dwordx4).
__device__ __forceinline__ void gl_lds16(const float* g, float* l){
  __builtin_amdgcn_global_load_lds(
      (const __attribute__((address_space(1))) unsigned int*)g,
      (__attribute__((address_space(3))) unsigned int*)l,
      16, 0, 0);
}

// grid = 2: block 0 builds the Y side (fyg), block 1 the X side (fxg).
__global__ __launch_bounds__(256) void k_prep(
    const float* __restrict__ h, const float* __restrict__ Ww,
    const float* __restrict__ Wb, int* __restrict__ meta,
    float* __restrict__ fyg, float* __restrict__ fxg)
{
  __shared__ float partial[32];      // [wave][slot]
  __shared__ float par_s[8];
  __shared__ float F[N_FILT*IMG_DIM];
  __shared__ int s_lo[64], s_hi[64], s_glo[16], s_ghi[16];
  __shared__ float ssum[4];
  const int t   = threadIdx.x;
  const int side= blockIdx.x;        // 0=Y, 1=X
  const int wv  = t>>6, ln = t&63;
  float* __restrict__ wout = side ? fxg : fyg;

  // zero-fill this side's weight buffer (packs only overwrite in-band rows)
  {
    float4 z = make_float4(0.f,0.f,0.f,0.f);
    float4* p = (float4*)wout;
    #pragma unroll
    for (int k=0;k<16;++k) p[t + 256*k] = z;
  }

  // ---- params[j] = h[0] . W_read_w[j] + W_read_b[j] (single pass over h) ----
  {
    float s0=0.f,s1=0.f,s2=0.f,s3=0.f,s4=0.f;
    for (int k=t;k<HDIM;k+=256){
      const float hv=h[k];
      s0=fmaf(hv,Ww[k        ],s0);
      s1=fmaf(hv,Ww[HDIM+k   ],s1);
      s2=fmaf(hv,Ww[2*HDIM+k ],s2);
      s3=fmaf(hv,Ww[3*HDIM+k ],s3);
      s4=fmaf(hv,Ww[4*HDIM+k ],s4);
    }
    #pragma unroll
    for (int o=32;o>0;o>>=1){
      s0+=__shfl_down(s0,o); s1+=__shfl_down(s1,o); s2+=__shfl_down(s2,o);
      s3+=__shfl_down(s3,o); s4+=__shfl_down(s4,o);
    }
    if (ln==0){ partial[wv*8+0]=s0; partial[wv*8+1]=s1; partial[wv*8+2]=s2;
                partial[wv*8+3]=s3; partial[wv*8+4]=s4; }
  }
  __syncthreads();
  if (t<5) par_s[t]=partial[t]+partial[8+t]+partial[16+t]+partial[24+t]+Wb[t];
  __syncthreads();

  const float var   = expf(par_s[2]+1e-8f);
  const float dt    = expf(par_s[3]);
  const float gamma = expf(par_s[4]);
  const float gC = 0.5f*257.f*(par_s[side?0:1]+1.f);  // Y<-par[1], X<-par[0]
  const float d  = dt*(255.f/63.f);
  const float sub= -32.5f*d;
  const float inv2v = 1.f/(2.f*var);
  const float w88v  = 88.f*var;   // band cutoff: e(a)/e(peak) >= exp(-44)

  if (t<64){
    float mu = gC + sub + d*(float)t;
    float astar = fminf(255.f, fmaxf(0.f, rintf(mu)));   // clamped peak
    float t0 = (astar-mu)*(astar-mu);
    float r  = sqrtf(t0 + w88v);
    int lo = (int)ceilf(mu-r); int hi = (int)floorf(mu+r)+1;
    lo = lo<0?0:lo; hi = hi>256?256:hi; if (hi<lo) hi=lo;
    s_lo[t]=lo; s_hi[t]=hi;
  }
  __syncthreads();
  if (t<16){
    int lo=256, hi=0;
    #pragma unroll
    for (int k2=0;k2<4;++k2){ lo=min(lo,s_lo[t*4+k2]); hi=max(hi,s_hi[t*4+k2]); }
    if (hi<lo){lo=0;hi=0;}
    if (side==0){ meta[t]=lo; meta[16+t]=hi; }
    else        { lo &= ~3;  meta[32+t]=lo; meta[48+t]=hi; }  // granule-aligned
    s_glo[t]=lo; s_ghi[t]=hi;
  }
  // F + global sum
  float sum=0.f;
  #pragma unroll
  for (int k=0;k<64;++k){
    int idx=t+256*k;
    int n=idx>>8, a=idx&255;
    float mu = gC+sub+d*(float)n;
    float dx=(float)a-mu;
    float e=expf(-dx*dx*inv2v);
    F[idx]=e; sum+=e;
  }
  #pragma unroll
  for (int o=32;o>0;o>>=1) sum+=__shfl_down(sum,o);
  if (ln==0) ssum[wv]=sum;
  __syncthreads();
  const float stot = ssum[0]+ssum[1]+ssum[2]+ssum[3];
  const float sc = (side==0 ? gamma : 1.f)/stot;   // fold gamma into Y side
  #pragma unroll
  for (int k=0;k<64;++k){
    int idx=t+256*k;
    int n=idx>>8, a=idx&255, g=n>>2;
    int lo=s_glo[g], hi=s_ghi[g];
    if (a>=lo && a<hi) wout[(size_t)((g<<10)+((a-lo)<<2)+(n&3))] = F[idx]*sc;
  }
}

// 4096 blocks: 4 blocks per image (16 filters each). 4 waves; wave w owns
// stage-1 n-group g=qq*4+w and stage-2 m-group q=w*4+(lane>>4).
// Stage 1: wave-private RING (8 slots, depth 6) of global_load_lds row-DMAs,
// constant s_waitcnt vmcnt(5) -> 6KB in flight per wave, no barriers.
// LDS overlay: POOL = stage-1 rings (4x8KB), then Tt + transpose buf (stage 2).
__global__ __launch_bounds__(256, 5) void k_main(
    const float* __restrict__ x, const float* __restrict__ xh,
    const int* __restrict__ meta, const float* __restrict__ fyg,
    const float* __restrict__ fxg, float* __restrict__ out)
{
  __shared__ float POOL[8192];      // 32 KiB total
  const int bid = blockIdx.x;
  const int lg  = ((bid&7)<<9) | (bid>>3);   // same-image quads -> same XCD
  const int img = lg>>2, qq = lg&3;
  const int tid = threadIdx.x;
  const int w    = __builtin_amdgcn_readfirstlane(tid>>6);
  const int lane = tid & 63;
  const float* __restrict__ src = (img<NBATCH) ? (x  + (size_t)img*IMG_SZ)
                                               : (xh + (size_t)(img-NBATCH)*IMG_SZ);
  float* __restrict__ dst = ((img<NBATCH) ? (out + (size_t)img*8192)
                                          : (out + (size_t)(img-NBATCH)*8192 + 4096))
                            + qq*1024;

  // ---- stage 1: T[n][b] = sum_a FY[n][a]*src[a][b]; lane owns cols 4L..4L+3 ----
  {
    const int g  = qq*4 + w;
    const int a0 = __builtin_amdgcn_readfirstlane(meta[g]);
    const int a1 = __builtin_amdgcn_readfirstlane(meta[16+g]);
    const int R  = a1 - a0;                    // rows in band (may be 0)
    float* const ckw = &POOL[w<<11];           // this wave's 8-slot ring (8 KiB)
    const float* const wp   = fyg + ((size_t)g<<10);   // [256][4] from a0
    const float* const srcL = src + (lane<<2);         // +16B per lane

    // prologue: fill pipeline to depth 6 (clamped rows are always valid)
    #pragma unroll
    for (int j=0;j<6;++j)
      gl_lds16(srcL + ((size_t)min(a0+j,255)<<8), ckw + (j<<8));

    float acc[4][4];
    #pragma unroll
    for (int k2=0;k2<4;++k2){acc[k2][0]=0.f;acc[k2][1]=0.f;acc[k2][2]=0.f;acc[k2][3]=0.f;}

    #pragma unroll 1
    for (int r=0; r<R; ++r){
      // issued so far = 6+r; allow 5 outstanding => rows 0..r have landed
      asm volatile("s_waitcnt vmcnt(5)" ::: "memory");
      __builtin_amdgcn_sched_barrier(0);
      // keep the pipe full: row r+6 -> slot (r+6)&7 (reuse distance 8 > depth 6)
      gl_lds16(srcL + ((size_t)min(a0+r+6,255)<<8), ckw + (((r+6)&7)<<8));
      const float4 tv = *(const float4*)&ckw[((r&7)<<8) + (lane<<2)];
      const float* wr = wp + (r<<2);           // wave-uniform -> s_load
      const float w0=wr[0], w1=wr[1], w2=wr[2], w3=wr[3];
      acc[0][0]=fmaf(w0,tv.x,acc[0][0]); acc[0][1]=fmaf(w0,tv.y,acc[0][1]);
      acc[0][2]=fmaf(w0,tv.z,acc[0][2]); acc[0][3]=fmaf(w0,tv.w,acc[0][3]);
      acc[1][0]=fmaf(w1,tv.x,acc[1][0]); acc[1][1]=fmaf(w1,tv.y,acc[1][1]);
      acc[1][2]=fmaf(w1,tv.z,acc[1][2]); acc[1][3]=fmaf(w1,tv.w,acc[1][3]);
      acc[2][0]=fmaf(w2,tv.x,acc[2][0]); acc[2][1]=fmaf(w2,tv.y,acc[2][1]);
      acc[2][2]=fmaf(w2,tv.z,acc[2][2]); acc[2][3]=fmaf(w2,tv.w,acc[2][3]);
      acc[3][0]=fmaf(w3,tv.x,acc[3][0]); acc[3][1]=fmaf(w3,tv.y,acc[3][1]);
      acc[3][2]=fmaf(w3,tv.z,acc[3][2]); acc[3][3]=fmaf(w3,tv.w,acc[3][3]);
    }
    // drain ALL DMA before the ring region is reused as Tt (overlay safety)
    asm volatile("s_waitcnt vmcnt(0)" ::: "memory");
    __syncthreads();
    // b128 writes into Tt = POOL[0..4095], granule-XOR swizzle (lane ^ n)
    #pragma unroll
    for (int k2=0;k2<4;++k2){
      const int n = w*4 + k2;                  // wave-uniform row (0..15)
      float4 v; v.x=acc[k2][0]; v.y=acc[k2][1]; v.z=acc[k2][2]; v.w=acc[k2][3];
      *(float4*)&POOL[(n<<8) + ((lane ^ n)<<2)] = v;
    }
  }
  __syncthreads();

  // ---- stage 2: out[n][m] = sum_b T[n][b]*FX[m][b]; lane = cc*16 + nl ----
  const int nl = lane & 15;
  const int cc = lane >> 4;
  const int q  = w*4 + cc;                     // one m-group of 4 per (wave,cc)
  const int lo4 = meta[32+q];
  const int hi  = meta[48+q];
  int ngu = (hi - lo4 + 3) >> 2;
  ngu = max(ngu, __shfl_xor(ngu,16));          // wave-uniform trip count
  ngu = max(ngu, __shfl_xor(ngu,32));          // (overrun iters: zero weights)
  const int u0  = lo4 >> 2;
  const float* wq = fxg + ((size_t)q<<10);     // [256][4] rows packed from lo4
  float o0=0.f,o1=0.f,o2=0.f,o3=0.f;
  #pragma unroll 1
  for (int it=0; it<ngu; it+=2){
    const int uA = min(u0+it,   63);
    const int uB = min(u0+it+1, 63);
    const float4 tvA = *(const float4*)&POOL[(nl<<8) + ((uA ^ nl)<<2)];
    const float4 tvB = *(const float4*)&POOL[(nl<<8) + ((uB ^ nl)<<2)];
    const float4 a0w = *(const float4*)(wq + it*16);
    const float4 a1w = *(const float4*)(wq + it*16 + 4);
    const float4 a2w = *(const float4*)(wq + it*16 + 8);
    const float4 a3w = *(const float4*)(wq + it*16 + 12);
    const float4 b0w = *(const float4*)(wq + it*16 + 16);
    const float4 b1w = *(const float4*)(wq + it*16 + 20);
    const float4 b2w = *(const float4*)(wq + it*16 + 24);
    const float4 b3w = *(const float4*)(wq + it*16 + 28);
    o0=fmaf(tvA.x,a0w.x,fmaf(tvA.y,a1w.x,fmaf(tvA.z,a2w.x,fmaf(tvA.w,a3w.x,o0))));
    o1=fmaf(tvA.x,a0w.y,fmaf(tvA.y,a1w.y,fmaf(tvA.z,a2w.y,fmaf(tvA.w,a3w.y,o1))));
    o2=fmaf(tvA.x,a0w.z,fmaf(tvA.y,a1w.z,fmaf(tvA.z,a2w.z,fmaf(tvA.w,a3w.z,o2))));
    o3=fmaf(tvA.x,a0w.w,fmaf(tvA.y,a1w.w,fmaf(tvA.z,a2w.w,fmaf(tvA.w,a3w.w,o3))));
    if (it+1 < ngu){
      o0=fmaf(tvB.x,b0w.x,fmaf(tvB.y,b1w.x,fmaf(tvB.z,b2w.x,fmaf(tvB.w,b3w.x,o0))));
      o1=fmaf(tvB.x,b0w.y,fmaf(tvB.y,b1w.y,fmaf(tvB.z,b2w.y,fmaf(tvB.w,b3w.y,o1))));
      o2=fmaf(tvB.x,b0w.z,fmaf(tvB.y,b1w.z,fmaf(tvB.z,b2w.z,fmaf(tvB.w,b3w.z,o2))));
      o3=fmaf(tvB.x,b0w.w,fmaf(tvB.y,b1w.w,fmaf(tvB.z,b2w.w,fmaf(tvB.w,b3w.w,o3))));
    }
  }
  __syncthreads();   // all stage-2 reads of POOL done before overwrite

  // ---- transpose via LDS (stride 68 keeps float4 16B-aligned), coalesced store ----
  {
    const int m0 = q*4;
    POOL[nl*68 + m0 + 0] = o0; POOL[nl*68 + m0 + 1] = o1;
    POOL[nl*68 + m0 + 2] = o2; POOL[nl*68 + m0 + 3] = o3;
  }
  __syncthreads();
  {
    const int f = tid*4;
    const int n = f>>6, m = f&63;
    const float4 v = *(const float4*)&POOL[n*68+m];
    *(float4*)(dst+f) = v;
  }
}

extern "C" void kernel_launch(void* const* d_in, const int* in_sizes, int n_in,
                              void* d_out, int out_size, void* d_ws, size_t ws_size,
                              hipStream_t stream)
{
  const float* x  = (const float*)d_in[0];
  const float* xh = (const float*)d_in[1];
  const float* h  = (const float*)d_in[2];   // only row 0 is used
  const float* Ww = (const float*)d_in[3];
  const float* Wb = (const float*)d_in[4];
  float* out = (float*)d_out;

  int*   meta = (int*)d_ws;
  float* fyg  = (float*)((char*)d_ws + 256);
  float* fxg  = (float*)((char*)d_ws + 256 + 65536);

  k_prep<<<2, 256, 0, stream>>>(h, Ww, Wb, meta, fyg, fxg);
  k_main<<<8*NBATCH, 256, 0, stream>>>(x, xh, meta, fyg, fxg, out);
}

// Round 8
// 92.623 us; speedup vs baseline: 1.5275x; 1.5275x over previous
//
#include <hip/hip_runtime.h>
#include <math.h>

#define N_FILT 64
#define IMG_DIM 256
#define IMG_SZ (256*256)
#define HDIM 1024
#define NBATCH 512

typedef __attribute__((ext_vector_type(4))) float f32x4;
typedef __attribute__((address_space(3))) float lds_float;

// ws layout (131,328 B total):
//   int meta[64]: [0..15]=aloY [16..31]=ahiY   (16 n-groups of 4, stage 1)
//                 [32..47]=lo4X (granule-aligned) [48..63]=hiX (16 m-groups of 4)
//   byte 256           : fyg [16][256][4] float (gamma/SY folded, zero-filled) 64 KiB
//   byte 256+65536     : fxg [16][256][4] float (1/SX folded, zero-filled)     64 KiB

// async DMA: one wave-issue copies 64 lanes x 16B = 1KB row into LDS at
// wave-uniform base + lane*16 (gfx950 global_load_lds_dwordx4).
__device__ __forceinline__ void gl_lds16(const float* g, float* l){
  __builtin_amdgcn_global_load_lds(
      (const __attribute__((address_space(1))) unsigned int*)g,
      (__attribute__((address_space(3))) unsigned int*)l,
      16, 0, 0);
}

// grid = 2: block 0 builds the Y side (fyg), block 1 the X side (fxg).
__global__ __launch_bounds__(256) void k_prep(
    const float* __restrict__ h, const float* __restrict__ Ww,
    const float* __restrict__ Wb, int* __restrict__ meta,
    float* __restrict__ fyg, float* __restrict__ fxg)
{
  __shared__ float partial[32];      // [wave][slot]
  __shared__ float par_s[8];
  __shared__ float F[N_FILT*IMG_DIM];
  __shared__ int s_lo[64], s_hi[64], s_glo[16], s_ghi[16];
  __shared__ float ssum[4];
  const int t   = threadIdx.x;
  const int side= blockIdx.x;        // 0=Y, 1=X
  const int wv  = t>>6, ln = t&63;
  float* __restrict__ wout = side ? fxg : fyg;

  // zero-fill this side's weight buffer (packs only overwrite in-band rows)
  {
    float4 z = make_float4(0.f,0.f,0.f,0.f);
    float4* p = (float4*)wout;
    #pragma unroll
    for (int k=0;k<16;++k) p[t + 256*k] = z;
  }

  // ---- params[j] = h[0] . W_read_w[j] + W_read_b[j] (single pass over h) ----
  {
    float s0=0.f,s1=0.f,s2=0.f,s3=0.f,s4=0.f;
    for (int k=t;k<HDIM;k+=256){
      const float hv=h[k];
      s0=fmaf(hv,Ww[k        ],s0);
      s1=fmaf(hv,Ww[HDIM+k   ],s1);
      s2=fmaf(hv,Ww[2*HDIM+k ],s2);
      s3=fmaf(hv,Ww[3*HDIM+k ],s3);
      s4=fmaf(hv,Ww[4*HDIM+k ],s4);
    }
    #pragma unroll
    for (int o=32;o>0;o>>=1){
      s0+=__shfl_down(s0,o); s1+=__shfl_down(s1,o); s2+=__shfl_down(s2,o);
      s3+=__shfl_down(s3,o); s4+=__shfl_down(s4,o);
    }
    if (ln==0){ partial[wv*8+0]=s0; partial[wv*8+1]=s1; partial[wv*8+2]=s2;
                partial[wv*8+3]=s3; partial[wv*8+4]=s4; }
  }
  __syncthreads();
  if (t<5) par_s[t]=partial[t]+partial[8+t]+partial[16+t]+partial[24+t]+Wb[t];
  __syncthreads();

  const float var   = expf(par_s[2]+1e-8f);
  const float dt    = expf(par_s[3]);
  const float gamma = expf(par_s[4]);
  const float gC = 0.5f*257.f*(par_s[side?0:1]+1.f);  // Y<-par[1], X<-par[0]
  const float d  = dt*(255.f/63.f);
  const float sub= -32.5f*d;
  const float inv2v = 1.f/(2.f*var);
  const float w88v  = 88.f*var;   // band cutoff: e(a)/e(peak) >= exp(-44)

  if (t<64){
    float mu = gC + sub + d*(float)t;
    float astar = fminf(255.f, fmaxf(0.f, rintf(mu)));   // clamped peak
    float t0 = (astar-mu)*(astar-mu);
    float r  = sqrtf(t0 + w88v);
    int lo = (int)ceilf(mu-r); int hi = (int)floorf(mu+r)+1;
    lo = lo<0?0:lo; hi = hi>256?256:hi; if (hi<lo) hi=lo;
    s_lo[t]=lo; s_hi[t]=hi;
  }
  __syncthreads();
  if (t<16){
    int lo=256, hi=0;
    #pragma unroll
    for (int k2=0;k2<4;++k2){ lo=min(lo,s_lo[t*4+k2]); hi=max(hi,s_hi[t*4+k2]); }
    if (hi<lo){lo=0;hi=0;}
    if (side==0){ meta[t]=lo; meta[16+t]=hi; }
    else        { lo &= ~3;  meta[32+t]=lo; meta[48+t]=hi; }  // granule-aligned
    s_glo[t]=lo; s_ghi[t]=hi;
  }
  // F + global sum
  float sum=0.f;
  #pragma unroll
  for (int k=0;k<64;++k){
    int idx=t+256*k;
    int n=idx>>8, a=idx&255;
    float mu = gC+sub+d*(float)n;
    float dx=(float)a-mu;
    float e=expf(-dx*dx*inv2v);
    F[idx]=e; sum+=e;
  }
  #pragma unroll
  for (int o=32;o>0;o>>=1) sum+=__shfl_down(sum,o);
  if (ln==0) ssum[wv]=sum;
  __syncthreads();
  const float stot = ssum[0]+ssum[1]+ssum[2]+ssum[3];
  const float sc = (side==0 ? gamma : 1.f)/stot;   // fold gamma into Y side
  #pragma unroll
  for (int k=0;k<64;++k){
    int idx=t+256*k;
    int n=idx>>8, a=idx&255, g=n>>2;
    int lo=s_glo[g], hi=s_ghi[g];
    if (a>=lo && a<hi) wout[(size_t)((g<<10)+((a-lo)<<2)+(n&3))] = F[idx]*sc;
  }
}

// 4096 blocks: 4 blocks per image (16 filters each). 4 waves; wave w owns
// stage-1 n-group g=qq*4+w and stage-2 m-group q=w*4+(lane>>4).
// Stage 1: wave-private ring (4 slots x 2 rows) of global_load_lds DMAs,
// CLOBBER-FREE counted vmcnt (depth 3 chunks = 6KB/wave in flight) +
// asm ds_read_b128 consumption (rule-18 recipe: lgkmcnt(0)+sched_barrier).
__global__ __launch_bounds__(256, 5) void k_main(
    const float* __restrict__ x, const float* __restrict__ xh,
    const int* __restrict__ meta, const float* __restrict__ fyg,
    const float* __restrict__ fxg, float* __restrict__ out)
{
  __shared__ float POOL[8192];      // 32 KiB: 4 wave-rings; Tt overlaid later
  const int bid = blockIdx.x;
  const int lg  = ((bid&7)<<9) | (bid>>3);   // same-image quads -> same XCD
  const int img = lg>>2, qq = lg&3;
  const int tid = threadIdx.x;
  const int w    = __builtin_amdgcn_readfirstlane(tid>>6);
  const int lane = tid & 63;
  const float* __restrict__ src = (img<NBATCH) ? (x  + (size_t)img*IMG_SZ)
                                               : (xh + (size_t)(img-NBATCH)*IMG_SZ);
  float* __restrict__ dst = ((img<NBATCH) ? (out + (size_t)img*8192)
                                          : (out + (size_t)(img-NBATCH)*8192 + 4096))
                            + qq*1024;

  // ---- stage 1: T[n][b] = sum_a FY[n][a]*src[a][b]; lane owns cols 4L..4L+3 ----
  {
    const int g  = qq*4 + w;
    const int a0 = __builtin_amdgcn_readfirstlane(meta[g]);
    const int a1 = __builtin_amdgcn_readfirstlane(meta[16+g]);
    const int R  = a1 - a0;                    // rows in band (may be 0)
    const int CC = (R + 1) >> 1;               // 2-row chunks
    float* const ring = &POOL[w<<11];          // 8 KiB: 4 slots x 512 floats
    const float* const wp   = fyg + ((size_t)g<<10);   // [256][4], zero beyond band
    const float* const srcL = src + (lane<<2);         // +16B per lane

    float acc[4][4];
    #pragma unroll
    for (int k2=0;k2<4;++k2){acc[k2][0]=0.f;acc[k2][1]=0.f;acc[k2][2]=0.f;acc[k2][3]=0.f;}

#define SB0 __builtin_amdgcn_sched_barrier(0)
#define DMA2(ch) do{ const int _c=(ch); const int _r0=a0+2*_c; \
    gl_lds16(srcL + ((size_t)min(_r0,  255)<<8), ring + ((_c&3)<<9)); \
    gl_lds16(srcL + ((size_t)min(_r0+1,255)<<8), ring + ((_c&3)<<9) + 256); }while(0)
#define FMAROW(P,W) do{ \
    acc[0][0]=fmaf(W.x,P.x,acc[0][0]); acc[0][1]=fmaf(W.x,P.y,acc[0][1]); \
    acc[0][2]=fmaf(W.x,P.z,acc[0][2]); acc[0][3]=fmaf(W.x,P.w,acc[0][3]); \
    acc[1][0]=fmaf(W.y,P.x,acc[1][0]); acc[1][1]=fmaf(W.y,P.y,acc[1][1]); \
    acc[1][2]=fmaf(W.y,P.z,acc[1][2]); acc[1][3]=fmaf(W.y,P.w,acc[1][3]); \
    acc[2][0]=fmaf(W.z,P.x,acc[2][0]); acc[2][1]=fmaf(W.z,P.y,acc[2][1]); \
    acc[2][2]=fmaf(W.z,P.z,acc[2][2]); acc[2][3]=fmaf(W.z,P.w,acc[2][3]); \
    acc[3][0]=fmaf(W.w,P.x,acc[3][0]); acc[3][1]=fmaf(W.w,P.y,acc[3][1]); \
    acc[3][2]=fmaf(W.w,P.z,acc[3][2]); acc[3][3]=fmaf(W.w,P.w,acc[3][3]); }while(0)
// consume chunk k: asm ds_read x2 -> lgkmcnt(0) -> sched_barrier -> 32 FMAs.
// volatile-asm reads cannot be hoisted above the volatile-asm vmcnt wait.
#define CONSUME(k) do{ const int _k=(k); \
    lds_float* _l0 = (lds_float*)&ring[((_k&3)<<9) + (lane<<2)]; \
    lds_float* _l1 = (lds_float*)&ring[((_k&3)<<9) + 256 + (lane<<2)]; \
    f32x4 _t0, _t1; \
    asm volatile("ds_read_b128 %0, %1" : "=&v"(_t0) : "v"(_l0)); \
    asm volatile("ds_read_b128 %0, %1" : "=&v"(_t1) : "v"(_l1)); \
    const f32x4 _w0 = ((const f32x4*)wp)[2*_k]; \
    const f32x4 _w1 = ((const f32x4*)wp)[2*_k+1]; \
    asm volatile("s_waitcnt lgkmcnt(0)"); \
    SB0; \
    FMAROW(_t0,_w0); FMAROW(_t1,_w1); }while(0)

    if (R > 0){
      if (0 < CC) DMA2(0);
      if (1 < CC) DMA2(1);
      if (2 < CC) DMA2(2);
      int c = 0;
      #pragma unroll 1
      for (; c+3 < CC; ++c){
        DMA2(c+3);                              // 4 chunks (8 DMAs) in flight
        SB0; asm volatile("s_waitcnt vmcnt(6)"); SB0;   // chunk c landed
        CONSUME(c);
      }
      const int rem = CC - c;                   // 1..3 chunks outstanding
      if (rem == 3){
        SB0; asm volatile("s_waitcnt vmcnt(4)"); SB0; CONSUME(c);
        SB0; asm volatile("s_waitcnt vmcnt(2)"); SB0; CONSUME(c+1);
        SB0; asm volatile("s_waitcnt vmcnt(0)"); SB0; CONSUME(c+2);
      } else if (rem == 2){
        SB0; asm volatile("s_waitcnt vmcnt(2)"); SB0; CONSUME(c);
        SB0; asm volatile("s_waitcnt vmcnt(0)"); SB0; CONSUME(c+1);
      } else {
        SB0; asm volatile("s_waitcnt vmcnt(0)"); SB0; CONSUME(c);
      }
    }
    asm volatile("s_waitcnt vmcnt(0)");         // per-wave drain before overlay
#undef SB0
#undef DMA2
#undef FMAROW
#undef CONSUME
    __syncthreads();                            // all waves' DMAs retired
    // b128 writes into Tt = POOL[0..4095], granule-XOR swizzle (lane ^ n)
    #pragma unroll
    for (int k2=0;k2<4;++k2){
      const int n = w*4 + k2;                  // wave-uniform row (0..15)
      float4 v; v.x=acc[k2][0]; v.y=acc[k2][1]; v.z=acc[k2][2]; v.w=acc[k2][3];
      *(float4*)&POOL[(n<<8) + ((lane ^ n)<<2)] = v;
    }
  }
  __syncthreads();

  // ---- stage 2: out[n][m] = sum_b T[n][b]*FX[m][b]; lane = cc*16 + nl ----
  const int nl = lane & 15;
  const int cc = lane >> 4;
  const int q  = w*4 + cc;                     // one m-group of 4 per (wave,cc)
  const int lo4 = meta[32+q];
  const int hi  = meta[48+q];
  int ngu = (hi - lo4 + 3) >> 2;
  ngu = max(ngu, __shfl_xor(ngu,16));          // wave-uniform trip count
  ngu = max(ngu, __shfl_xor(ngu,32));          // (overrun iters: zero weights)
  const int u0  = lo4 >> 2;
  const float* wq = fxg + ((size_t)q<<10);     // [256][4] rows packed from lo4
  float o0=0.f,o1=0.f,o2=0.f,o3=0.f;
  #pragma unroll 1
  for (int it=0; it<ngu; it+=2){
    const int uA = min(u0+it,   63);
    const int uB = min(u0+it+1, 63);
    const float4 tvA = *(const float4*)&POOL[(nl<<8) + ((uA ^ nl)<<2)];
    const float4 tvB = *(const float4*)&POOL[(nl<<8) + ((uB ^ nl)<<2)];
    const float4 a0w = *(const float4*)(wq + it*16);
    const float4 a1w = *(const float4*)(wq + it*16 + 4);
    const float4 a2w = *(const float4*)(wq + it*16 + 8);
    const float4 a3w = *(const float4*)(wq + it*16 + 12);
    const float4 b0w = *(const float4*)(wq + it*16 + 16);
    const float4 b1w = *(const float4*)(wq + it*16 + 20);
    const float4 b2w = *(const float4*)(wq + it*16 + 24);
    const float4 b3w = *(const float4*)(wq + it*16 + 28);
    o0=fmaf(tvA.x,a0w.x,fmaf(tvA.y,a1w.x,fmaf(tvA.z,a2w.x,fmaf(tvA.w,a3w.x,o0))));
    o1=fmaf(tvA.x,a0w.y,fmaf(tvA.y,a1w.y,fmaf(tvA.z,a2w.y,fmaf(tvA.w,a3w.y,o1))));
    o2=fmaf(tvA.x,a0w.z,fmaf(tvA.y,a1w.z,fmaf(tvA.z,a2w.z,fmaf(tvA.w,a3w.z,o2))));
    o3=fmaf(tvA.x,a0w.w,fmaf(tvA.y,a1w.w,fmaf(tvA.z,a2w.w,fmaf(tvA.w,a3w.w,o3))));
    if (it+1 < ngu){
      o0=fmaf(tvB.x,b0w.x,fmaf(tvB.y,b1w.x,fmaf(tvB.z,b2w.x,fmaf(tvB.w,b3w.x,o0))));
      o1=fmaf(tvB.x,b0w.y,fmaf(tvB.y,b1w.y,fmaf(tvB.z,b2w.y,fmaf(tvB.w,b3w.y,o1))));
      o2=fmaf(tvB.x,b0w.z,fmaf(tvB.y,b1w.z,fmaf(tvB.z,b2w.z,fmaf(tvB.w,b3w.z,o2))));
      o3=fmaf(tvB.x,b0w.w,fmaf(tvB.y,b1w.w,fmaf(tvB.z,b2w.w,fmaf(tvB.w,b3w.w,o3))));
    }
  }
  __syncthreads();   // all stage-2 reads of POOL done before overwrite

  // ---- transpose via LDS (stride 68 keeps float4 16B-aligned), coalesced store ----
  {
    const int m0 = q*4;
    POOL[nl*68 + m0 + 0] = o0; POOL[nl*68 + m0 + 1] = o1;
    POOL[nl*68 + m0 + 2] = o2; POOL[nl*68 + m0 + 3] = o3;
  }
  __syncthreads();
  {
    const int f = tid*4;
    const int n = f>>6, m = f&63;
    const float4 v = *(const float4*)&POOL[n*68+m];
    *(float4*)(dst+f) = v;
  }
}

extern "C" void kernel_launch(void* const* d_in, const int* in_sizes, int n_in,
                              void* d_out, int out_size, void* d_ws, size_t ws_size,
                              hipStream_t stream)
{
  const float* x  = (const float*)d_in[0];
  const float* xh = (const float*)d_in[1];
  const float* h  = (const float*)d_in[2];   // only row 0 is used
  const float* Ww = (const float*)d_in[3];
  const float* Wb = (const float*)d_in[4];
  float* out = (float*)d_out;

  int*   meta = (int*)d_ws;
  float* fyg  = (float*)((char*)d_ws + 256);
  float* fxg  = (float*)((char*)d_ws + 256 + 65536);

  k_prep<<<2, 256, 0, stream>>>(h, Ww, Wb, meta, fyg, fxg);
  k_main<<<8*NBATCH, 256, 0, stream>>>(x, xh, meta, fyg, fxg, out);
}